// Round 2
// baseline (320.563 us; speedup 1.0000x reference)
//
#include <hip/hip_runtime.h>
#include <hip/hip_cooperative_groups.h>
#include <math.h>

namespace cg = cooperative_groups;

// B=2, C=O=256, H=W=64, K=33 offsets (D=4 rings).
//
// Algebra: aff[k,p] = Eg(p)·Ef(p_k) = G(p)·Ft(p_k) + const(p), with
// G = (Wf^T Wg)·Ftε + Wf^T bg; const(p) cancels in softmax.  Whole pipeline
// fused into ONE cooperative kernel (512 blocks = 2/CU co-resident) with
// grid.sync() between phases: M -> G-GEMM -> aff partials -> softmax+out.
typedef __attribute__((ext_vector_type(4))) float f4;

__device__ __forceinline__ int iclamp(int x, int lo, int hi) { return min(max(x, lo), hi); }

// k=0:(0,0); rings s=1..4: (-s,-s),(-s,0),(-s,s),(0,-s),(0,s),(s,-s),(s,0),(s,s)
__device__ constexpr int DXC[33] = {0, -1,-1,-1,0,0,1,1,1, -2,-2,-2,0,0,2,2,2, -3,-3,-3,0,0,3,3,3, -4,-4,-4,0,0,4,4,4};
__device__ constexpr int DYC[33] = {0, -1,0,1,-1,1,-1,0,1, -2,0,2,-2,2,-2,0,2, -3,0,3,-3,3,-3,0,3, -4,0,4,-4,4,-4,0,4};

// ---------------------------------------------------------------------------
// Phase 0: M[c1,c2] = sum_o Wf[o,c1]*Wg[o,c2]; r[c1] = sum_o Wf[o,c1]*bg[o].
// 64 block-works (8x8 of 32x32 tiles).
// ---------------------------------------------------------------------------
__device__ __forceinline__ void phase_M(
    float* LDSf, const float* __restrict__ Wf, const float* __restrict__ Wg,
    const float* __restrict__ bg, float* __restrict__ M, float* __restrict__ r,
    int bid, int tid)
{
    float (*Sf)[33] = (float(*)[33])LDSf;
    float (*Sg)[33] = (float(*)[33])(LDSf + 32 * 33);
    float (*Rs)[9]  = (float(*)[9])(LDSf + 2 * 32 * 33);
    const int c1b = (bid & 7) * 32, c2b = (bid >> 3) * 32;
    const int tx = tid & 15, ty = tid >> 4;
    float acc[2][2] = {};
    for (int ko = 0; ko < 256; ko += 32) {
        #pragma unroll
        for (int i = 0; i < 4; ++i) {
            int f = i * 256 + tid, o = f >> 5, c = f & 31;
            Sf[o][c] = Wf[(ko + o) * 256 + c1b + c];
            Sg[o][c] = Wg[(ko + o) * 256 + c2b + c];
        }
        __syncthreads();
        #pragma unroll
        for (int o = 0; o < 32; ++o) {
            float f0 = Sf[o][ty * 2], f1 = Sf[o][ty * 2 + 1];
            float g0 = Sg[o][tx * 2], g1 = Sg[o][tx * 2 + 1];
            acc[0][0] += f0 * g0; acc[0][1] += f0 * g1;
            acc[1][0] += f1 * g0; acc[1][1] += f1 * g1;
        }
        __syncthreads();
    }
    #pragma unroll
    for (int i = 0; i < 2; ++i)
        #pragma unroll
        for (int j = 0; j < 2; ++j)
            M[(size_t)(c1b + ty * 2 + i) * 256 + c2b + tx * 2 + j] = acc[i][j];

    if ((bid >> 3) == 0) {   // block-uniform
        const int c1l = tid & 31, og = tid >> 5;
        float s = 0.f;
        #pragma unroll 8
        for (int o = og * 32; o < og * 32 + 32; ++o)
            s += Wf[o * 256 + c1b + c1l] * bg[o];
        Rs[c1l][og] = s;
        __syncthreads();
        if (tid < 32) {
            float t = 0.f;
            #pragma unroll
            for (int j = 0; j < 8; ++j) t += Rs[tid][j];
            r[c1b + tid] = t;
        }
    }
}

// ---------------------------------------------------------------------------
// Phase 1: G[b][c1][p] = sum_c2 M[c1][c2]*Ftε[b][c2][p] + r[c1].
// 512 block-works: 64x64 tile each (bn 0..63, bm 0..3, b 0..1), 4x4 acc/thr.
// ---------------------------------------------------------------------------
__device__ __forceinline__ void phase_gemm(
    float* LDSf, const float* __restrict__ M, const float* __restrict__ r,
    const float* __restrict__ FtE, float* __restrict__ G,
    int bn, int bm, int b, int tid)
{
    float (*As)[68] = (float(*)[68])LDSf;               // [2*32][68] transposed
    float (*Bs)[64] = (float(*)[64])(LDSf + 64 * 68);   // [2*32][64]
    const float* X = FtE + (size_t)b * 256 * 4096;
    float* E = G + (size_t)b * 256 * 4096;
    const int tn = tid & 15, tm = tid >> 4;
    const int m0 = bm * 64, n0 = bn * 64;
    float acc[4][4] = {};
    f4 areg[2], breg[2];

    auto loadA = [&](int kk) {
        #pragma unroll
        for (int i = 0; i < 2; ++i) {
            int f = i * 256 + tid, m = f >> 3, cq = f & 7;
            areg[i] = *(const f4*)&M[(m0 + m) * 256 + kk + cq * 4];
        }
    };
    auto loadB = [&](int kk) {
        #pragma unroll
        for (int i = 0; i < 2; ++i) {
            int f = i * 256 + tid, c = f >> 4, n4 = f & 15;
            breg[i] = *(const f4*)&X[(size_t)(kk + c) * 4096 + n0 + n4 * 4];
        }
    };
    auto storeLDS = [&](int buf) {
        #pragma unroll
        for (int i = 0; i < 2; ++i) {
            int f = i * 256 + tid, m = f >> 3, cq = f & 7;
            As[buf * 32 + cq * 4 + 0][m] = areg[i].x;
            As[buf * 32 + cq * 4 + 1][m] = areg[i].y;
            As[buf * 32 + cq * 4 + 2][m] = areg[i].z;
            As[buf * 32 + cq * 4 + 3][m] = areg[i].w;
        }
        #pragma unroll
        for (int i = 0; i < 2; ++i) {
            int f = i * 256 + tid, c = f >> 4, n4 = f & 15;
            *(f4*)&Bs[buf * 32 + c][n4 * 4] = breg[i];
        }
    };

    loadA(0); loadB(0); storeLDS(0);
    __syncthreads();
    for (int ch = 0; ch < 8; ++ch) {
        const int buf = ch & 1;
        if (ch < 7) { loadA((ch + 1) * 32); loadB((ch + 1) * 32); }
        #pragma unroll 4
        for (int k = 0; k < 32; ++k) {
            f4 a  = *(const f4*)&As[buf * 32 + k][tm * 4];
            f4 bb = *(const f4*)&Bs[buf * 32 + k][tn * 4];
            #pragma unroll
            for (int ii = 0; ii < 4; ++ii)
                #pragma unroll
                for (int jj = 0; jj < 4; ++jj)
                    acc[ii][jj] += a[ii] * bb[jj];
        }
        if (ch < 7) storeLDS(buf ^ 1);
        __syncthreads();
    }
    #pragma unroll
    for (int ii = 0; ii < 4; ++ii) {
        int o = m0 + tm * 4 + ii;
        float bvs = r[o];
        f4 v = { acc[ii][0] + bvs, acc[ii][1] + bvs, acc[ii][2] + bvs, acc[ii][3] + bvs };
        *(f4*)&E[(size_t)o * 4096 + n0 + tn * 4] = v;
    }
}

// ---------------------------------------------------------------------------
// Phase 2: part[cseg][b][k][p] = sum_{c in cseg} G[c,p]*Ft[c,p+off_k].
// 512 block-works (64 h, 2 b, 4 cseg); 64 w x 4 k-groups; LDS dbuf
// [10 rows (9 Ft h-halo + 1 G)][8 ch][72 w-halo], w-halo pre-clamped.
// ---------------------------------------------------------------------------
template<int K0, int NK>
__device__ __forceinline__ void aff_accum(const float* __restrict__ base, float* __restrict__ aff)
{
    #pragma unroll
    for (int ch = 0; ch < 8; ++ch) {
        float eg = base[(72 + ch) * 72];          // d=9 row (G center)
        #pragma unroll
        for (int j = 0; j < NK; ++j) {
            constexpr int kk0 = K0;
            int k = kk0 + j;
            aff[j] += eg * base[((DXC[k] + 4) * 8 + ch) * 72 + DYC[k]];
        }
    }
}

__device__ __forceinline__ void phase_aff(
    float* LDSf, const float* __restrict__ Ftg, const float* __restrict__ Gc,
    float* __restrict__ part, int h, int b, int cseg, int tid)
{
    float (*L)[5760] = (float(*)[5760])LDSf;   // [2][10*8*72]
    const int w = tid & 63, kg = tid >> 6;     // kg wave-uniform
    const size_t plane = (size_t)b * 256 * 4096;
    const float* FtB = Ftg + plane;
    const float* GB  = Gc + plane;
    const int cbase = cseg * 64;

    int hr[10];
    #pragma unroll
    for (int d = 0; d < 10; ++d) hr[d] = (d < 9) ? iclamp(h + d - 4, 0, 63) : h;

    f4 vreg[5]; float sreg[3];

    auto load_rnd = [&](int rr) {
        const int c0 = cbase + rr * 8;
        #pragma unroll
        for (int i = 0; i < 5; ++i) {
            int f = i * 256 + tid, d = f >> 7, rem = f & 127, ch = rem >> 4, c4 = rem & 15;
            const float* src = (d < 9) ? FtB : GB;
            vreg[i] = *(const f4*)&src[(size_t)(c0 + ch) * 4096 + hr[d] * 64 + c4 * 4];
        }
        #pragma unroll
        for (int i = 0; i < 3; ++i) {
            int e = i * 256 + tid;
            if (e < 640) {
                int row = e >> 3, sc = e & 7, d = row >> 3, ch = row & 7;
                int wsrc = (sc < 4) ? 0 : 63;
                const float* src = (d < 9) ? FtB : GB;
                sreg[i] = src[(size_t)(c0 + ch) * 4096 + hr[d] * 64 + wsrc];
            }
        }
    };
    auto store_rnd = [&](int buf) {
        float* Lb = L[buf];
        #pragma unroll
        for (int i = 0; i < 5; ++i) {
            int f = i * 256 + tid, d = f >> 7, rem = f & 127, ch = rem >> 4, c4 = rem & 15;
            *(f4*)&Lb[(d * 8 + ch) * 72 + 4 + c4 * 4] = vreg[i];
        }
        #pragma unroll
        for (int i = 0; i < 3; ++i) {
            int e = i * 256 + tid;
            if (e < 640) {
                int row = e >> 3, sc = e & 7, d = row >> 3, ch = row & 7;
                int col = (sc < 4) ? sc : (64 + sc);
                Lb[(d * 8 + ch) * 72 + col] = sreg[i];
            }
        }
    };

    float aff[9] = {0.f,0.f,0.f,0.f,0.f,0.f,0.f,0.f,0.f};

    load_rnd(0); store_rnd(0);
    for (int rr = 0; rr < 8; ++rr) {
        if (rr < 7) load_rnd(rr + 1);
        __syncthreads();
        const float* base = &L[rr & 1][4 + w];
        switch (kg) {                      // wave-uniform branch
            case 0: aff_accum<0, 9>(base, aff); break;
            case 1: aff_accum<9, 8>(base, aff); break;
            case 2: aff_accum<17, 8>(base, aff); break;
            default: aff_accum<25, 8>(base, aff); break;
        }
        if (rr < 7) store_rnd((rr + 1) & 1);
    }

    const int k0 = (kg == 0) ? 0 : (kg == 1) ? 9 : (kg == 2) ? 17 : 25;
    const int nk = (kg == 0) ? 9 : 8;
    float* pB = part + (((size_t)cseg * 2 + b) * 33) * 4096 + h * 64 + w;
    #pragma unroll
    for (int j = 0; j < 9; ++j)            // compile-time j: aff[] stays in regs
        if (j < nk) pB[(size_t)(k0 + j) * 4096] = aff[j];
}

// ---------------------------------------------------------------------------
// Phase 3: fused softmax + out[c][p] = sum_k wgt[k,p]*Ft[c,p+off_k].
// 512 block-works, same staging skeleton; softmax 4-way redundant across waves.
// ---------------------------------------------------------------------------
__device__ __forceinline__ void phase_out(
    float* LDSf, const float* __restrict__ part, const float* __restrict__ Ft,
    float* __restrict__ out, int h, int b, int cseg, int tid)
{
    float (*L)[5184] = (float(*)[5184])LDSf;   // [2][9*8*72]
    const int w = tid & 63, cg = tid >> 6;     // cg wave-uniform
    const size_t plane = (size_t)b * 256 * 4096;
    const float* FtB = Ft + plane;
    float* outB = out + plane;
    const int cbase = cseg * 64;
    const int p = h * 64 + w;

    int hr[9];
    #pragma unroll
    for (int d = 0; d < 9; ++d) hr[d] = iclamp(h + d - 4, 0, 63);

    f4 vreg[5]; float sreg[3];

    auto load_rnd = [&](int rr) {
        const int c0 = cbase + rr * 8;
        #pragma unroll
        for (int i = 0; i < 5; ++i) {
            int f = i * 256 + tid;
            if (f < 1152) {
                int d = f >> 7, rem = f & 127, ch = rem >> 4, c4 = rem & 15;
                vreg[i] = *(const f4*)&FtB[(size_t)(c0 + ch) * 4096 + hr[d] * 64 + c4 * 4];
            }
        }
        #pragma unroll
        for (int i = 0; i < 3; ++i) {
            int e = i * 256 + tid;
            if (e < 576) {
                int row = e >> 3, sc = e & 7, d = row >> 3, ch = row & 7;
                int wsrc = (sc < 4) ? 0 : 63;
                sreg[i] = FtB[(size_t)(c0 + ch) * 4096 + hr[d] * 64 + wsrc];
            }
        }
    };
    auto store_rnd = [&](int buf) {
        float* Lb = L[buf];
        #pragma unroll
        for (int i = 0; i < 5; ++i) {
            int f = i * 256 + tid;
            if (f < 1152) {
                int d = f >> 7, rem = f & 127, ch = rem >> 4, c4 = rem & 15;
                *(f4*)&Lb[(d * 8 + ch) * 72 + 4 + c4 * 4] = vreg[i];
            }
        }
        #pragma unroll
        for (int i = 0; i < 3; ++i) {
            int e = i * 256 + tid;
            if (e < 576) {
                int row = e >> 3, sc = e & 7, d = row >> 3, ch = row & 7;
                int col = (sc < 4) ? sc : (64 + sc);
                Lb[(d * 8 + ch) * 72 + col] = sreg[i];
            }
        }
    };

    load_rnd(0);

    // ---- per-pixel softmax over k ----
    float wv[33];
    {
        constexpr size_t CS = (size_t)2 * 33 * 4096;   // cseg stride in part
        const float* pB = part + ((size_t)b * 33) * 4096 + p;
        float mx = -INFINITY;
        #pragma unroll
        for (int k = 0; k < 33; ++k) {
            size_t off = (size_t)k * 4096;
            float s = pB[off] + pB[CS + off] + pB[2 * CS + off] + pB[3 * CS + off];
            bool valid = ((unsigned)(h + DXC[k]) < 64u) && ((unsigned)(w + DYC[k]) < 64u);
            wv[k] = valid ? s : -INFINITY;
            mx = fmaxf(mx, wv[k]);
        }
        float ssum = 0.f;
        #pragma unroll
        for (int k = 0; k < 33; ++k) { float e = __expf(wv[k] - mx); wv[k] = e; ssum += e; }
        float inv = 1.0f / ssum;
        #pragma unroll
        for (int k = 0; k < 33; ++k) wv[k] *= inv;
    }

    store_rnd(0);
    for (int rr = 0; rr < 8; ++rr) {
        if (rr < 7) load_rnd(rr + 1);
        __syncthreads();
        const float* base = &L[rr & 1][4 + w];
        #pragma unroll
        for (int u = 0; u < 2; ++u) {
            const float* b2 = base + (cg * 2 + u) * 72;
            float o = 0.f;
            #pragma unroll
            for (int k = 0; k < 33; ++k)
                o += wv[k] * b2[(DXC[k] + 4) * 576 + DYC[k]];
            int c = cbase + rr * 8 + cg * 2 + u;
            outB[(size_t)c * 4096 + p] = o;
        }
        if (rr < 7) store_rnd((rr + 1) & 1);
    }
}

// ---------------------------------------------------------------------------
// Fused cooperative kernel: 512 blocks x 256 threads, 2 blocks/CU.
// LDS union sized for the largest phase (aff: 2 x 5760 floats = 46.1 KB).
// ---------------------------------------------------------------------------
__global__ __launch_bounds__(256, 2) void fused_all(
    const float* __restrict__ Wf, const float* __restrict__ Wg,
    const float* __restrict__ bg, const float* __restrict__ Ft,
    const float* __restrict__ FtE, float* __restrict__ Mw, float* __restrict__ rw,
    float* __restrict__ G, float* __restrict__ part, float* __restrict__ out)
{
    __shared__ float LDS[11520];
    cg::grid_group grid = cg::this_grid();
    const int bid = blockIdx.x, tid = threadIdx.x;

    if (bid < 64) phase_M(LDS, Wf, Wg, bg, Mw, rw, bid, tid);
    grid.sync();
    phase_gemm(LDS, Mw, rw, FtE, G, bid & 63, (bid >> 6) & 3, bid >> 8, tid);
    grid.sync();
    phase_aff(LDS, Ft, G, part, bid & 63, (bid >> 6) & 1, bid >> 7, tid);
    grid.sync();
    phase_out(LDS, part, Ft, out, bid & 63, (bid >> 6) & 1, bid >> 7, tid);
}

// ---------------------------------------------------------------------------
// Fallback (non-cooperative) path: same phases as 4 dispatches.
// ---------------------------------------------------------------------------
__global__ __launch_bounds__(256) void k_M(
    const float* __restrict__ Wf, const float* __restrict__ Wg,
    const float* __restrict__ bg, float* __restrict__ M, float* __restrict__ r)
{
    __shared__ float LDS[2 * 32 * 33 + 32 * 9];
    phase_M(LDS, Wf, Wg, bg, M, r, blockIdx.x, threadIdx.x);
}

__global__ __launch_bounds__(256, 2) void k_gemm(
    const float* __restrict__ M, const float* __restrict__ r,
    const float* __restrict__ FtE, float* __restrict__ G)
{
    __shared__ float LDS[64 * 68 + 64 * 64];
    const int bid = blockIdx.x;
    phase_gemm(LDS, M, r, FtE, G, bid & 63, (bid >> 6) & 3, bid >> 8, threadIdx.x);
}

__global__ __launch_bounds__(256, 2) void k_aff(
    const float* __restrict__ Ft, const float* __restrict__ G,
    float* __restrict__ part)
{
    __shared__ float LDS[2 * 5760];
    const int bid = blockIdx.x;
    phase_aff(LDS, Ft, G, part, bid & 63, (bid >> 6) & 1, bid >> 7, threadIdx.x);
}

__global__ __launch_bounds__(256, 2) void k_out(
    const float* __restrict__ part, const float* __restrict__ Ft,
    float* __restrict__ out)
{
    __shared__ float LDS[2 * 5184];
    const int bid = blockIdx.x;
    phase_out(LDS, part, Ft, out, bid & 63, (bid >> 6) & 1, bid >> 7, threadIdx.x);
}

// ---------------------------------------------------------------------------
extern "C" void kernel_launch(void* const* d_in, const int* in_sizes, int n_in,
                              void* d_out, int out_size, void* d_ws, size_t ws_size,
                              hipStream_t stream) {
    const float* Ft  = (const float*)d_in[0];
    const float* FtE = (const float*)d_in[1];
    const float* Wf  = (const float*)d_in[2];
    const float* bf  = (const float*)d_in[3];
    const float* Wg  = (const float*)d_in[4];
    const float* bg  = (const float*)d_in[5];
    float* out = (float*)d_out;
    (void)bf;   // bf contributes only a k-constant -> cancelled by softmax

    // ws: G 8.4MB | part 4.3MB | M 256KB | r 1KB
    float* G    = (float*)d_ws;
    float* part = G + (size_t)2 * 256 * 4096;        // [4 cseg][2 b][33][4096]
    float* Mw   = part + (size_t)4 * 2 * 33 * 4096;  // [256][256]
    float* rw   = Mw + 256 * 256;                    // [256]

    void* args[10] = { (void*)&Wf, (void*)&Wg, (void*)&bg, (void*)&Ft, (void*)&FtE,
                       (void*)&Mw, (void*)&rw, (void*)&G, (void*)&part, (void*)&out };
    hipError_t err = hipLaunchCooperativeKernel(
        reinterpret_cast<const void*>(&fused_all), dim3(512), dim3(256),
        args, 0, stream);
    if (err != hipSuccess) {
        // Non-cooperative fallback: identical math as 4 dispatches.
        hipLaunchKernelGGL(k_M,    dim3(64),  dim3(256), 0, stream, Wf, Wg, bg, Mw, rw);
        hipLaunchKernelGGL(k_gemm, dim3(512), dim3(256), 0, stream, Mw, rw, FtE, G);
        hipLaunchKernelGGL(k_aff,  dim3(512), dim3(256), 0, stream, Ft, G, part);
        hipLaunchKernelGGL(k_out,  dim3(512), dim3(256), 0, stream, part, Ft, out);
    }
}

// Round 3
// 141.038 us; speedup vs baseline: 2.2729x; 2.2729x over previous
//
#include <hip/hip_runtime.h>
#include <math.h>

// B=2, C=O=256, H=W=64, K=33 offsets (D=4 rings).
//
// Algebra: aff[k,p] = Eg(p)·Ef(p_k) = G(p)·Ft(p_k) + const(p), with
// G = (Wf^T Wg)·Ftε + Wf^T bg; const(p) cancels in softmax.
// Pipeline: mat_M (64 blk) -> gemm_G (512 blk, 64x64 tile, 2 blk/CU)
//        -> aff_part (512 blk) -> out_kernel (512 blk, fused softmax).
typedef __attribute__((ext_vector_type(4))) float f4;

__device__ __forceinline__ int iclamp(int x, int lo, int hi) { return min(max(x, lo), hi); }

// k=0:(0,0); rings s=1..4: (-s,-s),(-s,0),(-s,s),(0,-s),(0,s),(s,-s),(s,0),(s,s)
__device__ constexpr int DXC[33] = {0, -1,-1,-1,0,0,1,1,1, -2,-2,-2,0,0,2,2,2, -3,-3,-3,0,0,3,3,3, -4,-4,-4,0,0,4,4,4};
__device__ constexpr int DYC[33] = {0, -1,0,1,-1,1,-1,0,1, -2,0,2,-2,2,-2,0,2, -3,0,3,-3,3,-3,0,3, -4,0,4,-4,4,-4,0,4};

// ---------------------------------------------------------------------------
// mat_M: M[c1,c2] = sum_o Wf[o,c1]*Wg[o,c2]; r[c1] = sum_o Wf[o,c1]*bg[o].
// grid (8,8) = 64 blocks (32x32 tiles, 2x2 acc).
// ---------------------------------------------------------------------------
__global__ __launch_bounds__(256) void mat_M(
    const float* __restrict__ Wf, const float* __restrict__ Wg,
    const float* __restrict__ bg, float* __restrict__ M, float* __restrict__ r)
{
    __shared__ float Sf[32][33], Sg[32][33];
    __shared__ float Rs[32][9];
    const int c1b = blockIdx.x * 32, c2b = blockIdx.y * 32;
    const int tid = threadIdx.x;
    const int tx = tid & 15, ty = tid >> 4;
    float acc[2][2] = {};
    for (int ko = 0; ko < 256; ko += 32) {
        #pragma unroll
        for (int i = 0; i < 4; ++i) {
            int f = i * 256 + tid, o = f >> 5, c = f & 31;
            Sf[o][c] = Wf[(ko + o) * 256 + c1b + c];
            Sg[o][c] = Wg[(ko + o) * 256 + c2b + c];
        }
        __syncthreads();
        #pragma unroll
        for (int o = 0; o < 32; ++o) {
            float f0 = Sf[o][ty * 2], f1 = Sf[o][ty * 2 + 1];
            float g0 = Sg[o][tx * 2], g1 = Sg[o][tx * 2 + 1];
            acc[0][0] += f0 * g0; acc[0][1] += f0 * g1;
            acc[1][0] += f1 * g0; acc[1][1] += f1 * g1;
        }
        __syncthreads();
    }
    #pragma unroll
    for (int i = 0; i < 2; ++i)
        #pragma unroll
        for (int j = 0; j < 2; ++j)
            M[(size_t)(c1b + ty * 2 + i) * 256 + c2b + tx * 2 + j] = acc[i][j];

    if (blockIdx.y == 0) {   // block-uniform
        const int c1l = tid & 31, og = tid >> 5;
        float s = 0.f;
        #pragma unroll 8
        for (int o = og * 32; o < og * 32 + 32; ++o)
            s += Wf[o * 256 + c1b + c1l] * bg[o];
        Rs[c1l][og] = s;
        __syncthreads();
        if (tid < 32) {
            float t = 0.f;
            #pragma unroll
            for (int j = 0; j < 8; ++j) t += Rs[tid][j];
            r[c1b + tid] = t;
        }
    }
}

// ---------------------------------------------------------------------------
// gemm_G: G[b][c1][p] = sum_c2 M[c1][c2]*Ftε[b][c2][p] + r[c1].
// Grid 512 blocks (bn 0..63, bm 0..3, b 0..1): 64x64 tile, 4x4 acc/thread,
// 2 blocks/CU co-resident (latency hiding across the k-loop barriers).
// ---------------------------------------------------------------------------
__global__ __launch_bounds__(256, 2) void gemm_G(
    const float* __restrict__ M, const float* __restrict__ r,
    const float* __restrict__ FtE, float* __restrict__ G)
{
    __shared__ float As[64][68];   // [2buf*32 k][c1], transposed, pad 68
    __shared__ float Bs[64][64];   // [2buf*32 k][p]

    const int bid = blockIdx.x;
    const int bn = bid & 63, bm = (bid >> 6) & 3, b = bid >> 8;
    const float* X = FtE + (size_t)b * 256 * 4096;
    float* E = G + (size_t)b * 256 * 4096;
    const int tid = threadIdx.x;
    const int tn = tid & 15, tm = tid >> 4;
    const int m0 = bm * 64, n0 = bn * 64;
    float acc[4][4] = {};
    f4 areg[2], breg[2];

    auto loadA = [&](int kk) {
        #pragma unroll
        for (int i = 0; i < 2; ++i) {
            int f = i * 256 + tid, m = f >> 3, cq = f & 7;
            areg[i] = *(const f4*)&M[(m0 + m) * 256 + kk + cq * 4];
        }
    };
    auto loadB = [&](int kk) {
        #pragma unroll
        for (int i = 0; i < 2; ++i) {
            int f = i * 256 + tid, c = f >> 4, n4 = f & 15;
            breg[i] = *(const f4*)&X[(size_t)(kk + c) * 4096 + n0 + n4 * 4];
        }
    };
    auto storeLDS = [&](int buf) {
        #pragma unroll
        for (int i = 0; i < 2; ++i) {
            int f = i * 256 + tid, m = f >> 3, cq = f & 7;
            As[buf * 32 + cq * 4 + 0][m] = areg[i].x;
            As[buf * 32 + cq * 4 + 1][m] = areg[i].y;
            As[buf * 32 + cq * 4 + 2][m] = areg[i].z;
            As[buf * 32 + cq * 4 + 3][m] = areg[i].w;
        }
        #pragma unroll
        for (int i = 0; i < 2; ++i) {
            int f = i * 256 + tid, c = f >> 4, n4 = f & 15;
            *(f4*)&Bs[buf * 32 + c][n4 * 4] = breg[i];
        }
    };

    loadA(0); loadB(0); storeLDS(0);
    __syncthreads();
    for (int ch = 0; ch < 8; ++ch) {
        const int buf = ch & 1;
        if (ch < 7) { loadA((ch + 1) * 32); loadB((ch + 1) * 32); }
        #pragma unroll 4
        for (int k = 0; k < 32; ++k) {
            f4 a  = *(const f4*)&As[buf * 32 + k][tm * 4];
            f4 bb = *(const f4*)&Bs[buf * 32 + k][tn * 4];
            #pragma unroll
            for (int ii = 0; ii < 4; ++ii)
                #pragma unroll
                for (int jj = 0; jj < 4; ++jj)
                    acc[ii][jj] += a[ii] * bb[jj];
        }
        if (ch < 7) storeLDS(buf ^ 1);
        __syncthreads();
    }
    #pragma unroll
    for (int ii = 0; ii < 4; ++ii) {
        int o = m0 + tm * 4 + ii;
        float bvs = r[o];
        f4 v = { acc[ii][0] + bvs, acc[ii][1] + bvs, acc[ii][2] + bvs, acc[ii][3] + bvs };
        *(f4*)&E[(size_t)o * 4096 + n0 + tn * 4] = v;
    }
}

// ---------------------------------------------------------------------------
// aff_part: part[cseg][b][k][p] = sum_{c in cseg's 64} G[c,p]*Ft[c,p+off_k]
// grid (64 h, 2 b, 4 cseg) = 512 blocks, block 256 = 64 w x 4 k-groups.
// LDS dbuf [10 rows (9 Ft h-halo + 1 G)][8 ch][72 w-halo], w-halo pre-clamped.
// ---------------------------------------------------------------------------
template<int K0, int NK>
__device__ __forceinline__ void aff_accum(const float* __restrict__ base, float* __restrict__ aff)
{
    #pragma unroll
    for (int ch = 0; ch < 8; ++ch) {
        float eg = base[(72 + ch) * 72];          // d=9 row (G center)
        #pragma unroll
        for (int j = 0; j < NK; ++j) {
            constexpr int kk0 = K0;
            int k = kk0 + j;
            aff[j] += eg * base[((DXC[k] + 4) * 8 + ch) * 72 + DYC[k]];
        }
    }
}

__global__ __launch_bounds__(256, 2) void aff_part(
    const float* __restrict__ Ftg, const float* __restrict__ Gc,
    float* __restrict__ part)
{
    __shared__ float L[2][10 * 8 * 72];   // [d][ch][72]

    const int h = blockIdx.x, b = blockIdx.y, cseg = blockIdx.z;
    const int tid = threadIdx.x;
    const int w = tid & 63, kg = tid >> 6;    // kg wave-uniform
    const size_t plane = (size_t)b * 256 * 4096;
    const float* FtB = Ftg + plane;
    const float* GB  = Gc + plane;
    const int cbase = cseg * 64;

    int hr[10];
    #pragma unroll
    for (int d = 0; d < 10; ++d) hr[d] = (d < 9) ? iclamp(h + d - 4, 0, 63) : h;

    f4 vreg[5]; float sreg[3];

    auto load_rnd = [&](int rr) {
        const int c0 = cbase + rr * 8;
        #pragma unroll
        for (int i = 0; i < 5; ++i) {
            int f = i * 256 + tid, d = f >> 7, rem = f & 127, ch = rem >> 4, c4 = rem & 15;
            const float* src = (d < 9) ? FtB : GB;
            vreg[i] = *(const f4*)&src[(size_t)(c0 + ch) * 4096 + hr[d] * 64 + c4 * 4];
        }
        #pragma unroll
        for (int i = 0; i < 3; ++i) {
            int e = i * 256 + tid;
            if (e < 640) {
                int row = e >> 3, sc = e & 7, d = row >> 3, ch = row & 7;
                int wsrc = (sc < 4) ? 0 : 63;
                const float* src = (d < 9) ? FtB : GB;
                sreg[i] = src[(size_t)(c0 + ch) * 4096 + hr[d] * 64 + wsrc];
            }
        }
    };
    auto store_rnd = [&](int buf) {
        float* Lb = L[buf];
        #pragma unroll
        for (int i = 0; i < 5; ++i) {
            int f = i * 256 + tid, d = f >> 7, rem = f & 127, ch = rem >> 4, c4 = rem & 15;
            *(f4*)&Lb[(d * 8 + ch) * 72 + 4 + c4 * 4] = vreg[i];
        }
        #pragma unroll
        for (int i = 0; i < 3; ++i) {
            int e = i * 256 + tid;
            if (e < 640) {
                int row = e >> 3, sc = e & 7, d = row >> 3, ch = row & 7;
                int col = (sc < 4) ? sc : (64 + sc);
                Lb[(d * 8 + ch) * 72 + col] = sreg[i];
            }
        }
    };

    float aff[9] = {0.f,0.f,0.f,0.f,0.f,0.f,0.f,0.f,0.f};

    load_rnd(0); store_rnd(0);
    for (int rr = 0; rr < 8; ++rr) {
        if (rr < 7) load_rnd(rr + 1);
        __syncthreads();
        const float* base = &L[rr & 1][4 + w];
        switch (kg) {                      // wave-uniform branch
            case 0: aff_accum<0, 9>(base, aff); break;
            case 1: aff_accum<9, 8>(base, aff); break;
            case 2: aff_accum<17, 8>(base, aff); break;
            default: aff_accum<25, 8>(base, aff); break;
        }
        if (rr < 7) store_rnd((rr + 1) & 1);
    }

    const int k0 = (kg == 0) ? 0 : (kg == 1) ? 9 : (kg == 2) ? 17 : 25;
    const int nk = (kg == 0) ? 9 : 8;
    float* pB = part + (((size_t)cseg * 2 + b) * 33) * 4096 + h * 64 + w;
    #pragma unroll
    for (int j = 0; j < 9; ++j)            // compile-time j: aff[] stays in regs
        if (j < nk) pB[(size_t)(k0 + j) * 4096] = aff[j];
}

// ---------------------------------------------------------------------------
// out (fused softmax): per thread, sum 4 cseg partials -> mask -> softmax
// (4-way redundant across cg waves; part is L2-resident), then
// out[c][p] = sum_k wgt[k,p]*Ft[c,p+off_k]. Invalid k: wgt==0 -> clamped
// gather contributes 0.
// ---------------------------------------------------------------------------
__global__ __launch_bounds__(256, 2) void out_kernel(
    const float* __restrict__ part, const float* __restrict__ Ft,
    float* __restrict__ out)
{
    __shared__ float L[2][9 * 8 * 72];

    const int h = blockIdx.x, b = blockIdx.y, cseg = blockIdx.z;
    const int tid = threadIdx.x;
    const int w = tid & 63, cg = tid >> 6;    // cg wave-uniform
    const size_t plane = (size_t)b * 256 * 4096;
    const float* FtB = Ft + plane;
    float* outB = out + plane;
    const int cbase = cseg * 64;
    const int p = h * 64 + w;

    int hr[9];
    #pragma unroll
    for (int d = 0; d < 9; ++d) hr[d] = iclamp(h + d - 4, 0, 63);

    f4 vreg[5]; float sreg[3];

    auto load_rnd = [&](int rr) {
        const int c0 = cbase + rr * 8;
        #pragma unroll
        for (int i = 0; i < 5; ++i) {
            int f = i * 256 + tid;
            if (f < 1152) {
                int d = f >> 7, rem = f & 127, ch = rem >> 4, c4 = rem & 15;
                vreg[i] = *(const f4*)&FtB[(size_t)(c0 + ch) * 4096 + hr[d] * 64 + c4 * 4];
            }
        }
        #pragma unroll
        for (int i = 0; i < 3; ++i) {
            int e = i * 256 + tid;
            if (e < 576) {
                int row = e >> 3, sc = e & 7, d = row >> 3, ch = row & 7;
                int wsrc = (sc < 4) ? 0 : 63;
                sreg[i] = FtB[(size_t)(c0 + ch) * 4096 + hr[d] * 64 + wsrc];
            }
        }
    };
    auto store_rnd = [&](int buf) {
        float* Lb = L[buf];
        #pragma unroll
        for (int i = 0; i < 5; ++i) {
            int f = i * 256 + tid;
            if (f < 1152) {
                int d = f >> 7, rem = f & 127, ch = rem >> 4, c4 = rem & 15;
                *(f4*)&Lb[(d * 8 + ch) * 72 + 4 + c4 * 4] = vreg[i];
            }
        }
        #pragma unroll
        for (int i = 0; i < 3; ++i) {
            int e = i * 256 + tid;
            if (e < 576) {
                int row = e >> 3, sc = e & 7, d = row >> 3, ch = row & 7;
                int col = (sc < 4) ? sc : (64 + sc);
                Lb[(d * 8 + ch) * 72 + col] = sreg[i];
            }
        }
    };

    load_rnd(0);

    // ---- per-pixel softmax over k ----
    float wv[33];
    {
        constexpr size_t CS = (size_t)2 * 33 * 4096;   // cseg stride in part
        const float* pB = part + ((size_t)b * 33) * 4096 + p;
        float mx = -INFINITY;
        #pragma unroll
        for (int k = 0; k < 33; ++k) {
            size_t off = (size_t)k * 4096;
            float s = pB[off] + pB[CS + off] + pB[2 * CS + off] + pB[3 * CS + off];
            bool valid = ((unsigned)(h + DXC[k]) < 64u) && ((unsigned)(w + DYC[k]) < 64u);
            wv[k] = valid ? s : -INFINITY;
            mx = fmaxf(mx, wv[k]);
        }
        float ssum = 0.f;
        #pragma unroll
        for (int k = 0; k < 33; ++k) { float e = __expf(wv[k] - mx); wv[k] = e; ssum += e; }
        float inv = 1.0f / ssum;
        #pragma unroll
        for (int k = 0; k < 33; ++k) wv[k] *= inv;
    }

    store_rnd(0);
    for (int rr = 0; rr < 8; ++rr) {
        if (rr < 7) load_rnd(rr + 1);
        __syncthreads();
        const float* base = &L[rr & 1][4 + w];
        #pragma unroll
        for (int u = 0; u < 2; ++u) {
            const float* b2 = base + (cg * 2 + u) * 72;
            float o = 0.f;
            #pragma unroll
            for (int k = 0; k < 33; ++k)
                o += wv[k] * b2[(DXC[k] + 4) * 576 + DYC[k]];
            int c = cbase + rr * 8 + cg * 2 + u;
            outB[(size_t)c * 4096 + p] = o;
        }
        if (rr < 7) store_rnd((rr + 1) & 1);
    }
}

// ---------------------------------------------------------------------------
extern "C" void kernel_launch(void* const* d_in, const int* in_sizes, int n_in,
                              void* d_out, int out_size, void* d_ws, size_t ws_size,
                              hipStream_t stream) {
    const float* Ft  = (const float*)d_in[0];
    const float* FtE = (const float*)d_in[1];
    const float* Wf  = (const float*)d_in[2];
    const float* bf  = (const float*)d_in[3];
    const float* Wg  = (const float*)d_in[4];
    const float* bg  = (const float*)d_in[5];
    float* out = (float*)d_out;
    (void)bf;   // bf contributes only a k-constant -> cancelled by softmax

    // ws: G 8.4MB | part 4.3MB | M 256KB | r 1KB
    float* G    = (float*)d_ws;
    float* part = G + (size_t)2 * 256 * 4096;        // [4 cseg][2 b][33][4096]
    float* Mw   = part + (size_t)4 * 2 * 33 * 4096;  // [256][256]
    float* rw   = Mw + 256 * 256;                    // [256]

    hipLaunchKernelGGL(mat_M,      dim3(8, 8),     dim3(256), 0, stream, Wf, Wg, bg, Mw, rw);
    hipLaunchKernelGGL(gemm_G,     dim3(512),      dim3(256), 0, stream, Mw, rw, FtE, G);
    hipLaunchKernelGGL(aff_part,   dim3(64, 2, 4), dim3(256), 0, stream, Ft, G, part);
    hipLaunchKernelGGL(out_kernel, dim3(64, 2, 4), dim3(256), 0, stream, part, Ft, out);
}